// Round 6
// baseline (662.136 us; speedup 1.0000x reference)
//
#include <hip/hip_runtime.h>

// ---------------------------------------------------------------------------
// HedgeHog attention distillation map: pred = (fq.fk^T) rownorm, true = softmax(q0.k0^T/8)
// Output [2,2,16,2048,2048] fp32 = 1.07 GiB -> HBM-write-bound (~165us floor).
//
// v6: the vmcnt FIFO is shared by loads and stores -> any load-completion wait
// drains all older stores, collapsing the in-flight store window (Little's law
// -> ~2 TB/s). Fix: PREFETCH next chunk's MFMA B-operands into registers
// BEFORE issuing this chunk's stores; use raw s_barrier (no vmcnt(0) drain).
// Then every compiler wait is a counted vmcnt that spares the stores.
// 512-thr blocks (8 waves), 2 blocks/CU (16 waves/CU), double-buffered
// 16x256 LDS chunk, 1KB nt stores.
// ---------------------------------------------------------------------------

typedef __attribute__((ext_vector_type(8))) short  bf16x8;
typedef __attribute__((ext_vector_type(4))) float  f32x4;

#define NN 2048
#define NBH 32

__device__ float g_part[NBH * 8 * 128];   // fk colsum partials

__device__ __forceinline__ float bf2f(unsigned short u) {
  union { unsigned int i; float f; } v; v.i = ((unsigned int)u) << 16; return v.f;
}
__device__ __forceinline__ unsigned short f2bf(float f) {
  union { float f; unsigned int i; } v; v.f = f;
  unsigned int x = v.i;
  return (unsigned short)((x + 0x7FFFu + ((x >> 16) & 1u)) >> 16);  // RNE
}
__device__ __forceinline__ bf16x8 cvt8(const float* __restrict__ p) {
  bf16x8 v;
#pragma unroll
  for (int i = 0; i < 8; i++) v[i] = (short)f2bf(p[i]);
  return v;
}
__device__ __forceinline__ f32x4 mfma16(bf16x8 a, bf16x8 b, f32x4 c) {
  return __builtin_amdgcn_mfma_f32_16x16x32_bf16(a, b, c, 0, 0, 0);
}

// ---------------------------------------------------------------------------
// Kernel 1: projections + hedgehog features. One wave owns 16 rows.
// ---------------------------------------------------------------------------
__device__ __forceinline__ void proj_chain(
    const bf16x8 ax[2],
    const float* __restrict__ W1, const float* __restrict__ b1,
    const float* __restrict__ W2, const float* __restrict__ b2,
    unsigned short* __restrict__ o1w, unsigned short* __restrict__ o2w,
    unsigned short (*Tq)[72], unsigned short (*Tf)[136],
    long r0, int l15, int g, int l)
{
#pragma unroll
  for (int nt = 0; nt < 4; nt++) {
    f32x4 acc = {0.f, 0.f, 0.f, 0.f};
    acc = mfma16(ax[0], cvt8(W1 + (nt * 16 + l15) * 64 + g * 8), acc);
    acc = mfma16(ax[1], cvt8(W1 + (nt * 16 + l15) * 64 + 32 + g * 8), acc);
    float bv = b1[nt * 16 + l15];
#pragma unroll
    for (int j = 0; j < 4; j++)
      Tq[g * 4 + j][nt * 16 + l15] = f2bf(acc[j] + bv);   // C layout: row=(l>>4)*4+j, col=l&15
  }
#pragma unroll
  for (int i = 0; i < 2; i++) {
    int c = i * 64 + l;
    int r = c >> 3, cc = c & 7;
    *(bf16x8*)(o1w + (r0 + r) * 64 + cc * 8) = *(const bf16x8*)&Tq[r][cc * 8];
  }
  bf16x8 a1[2];
#pragma unroll
  for (int kk = 0; kk < 2; kk++)
    a1[kk] = *(const bf16x8*)&Tq[l15][kk * 32 + g * 8];
#pragma unroll
  for (int nt = 0; nt < 4; nt++) {
    f32x4 acc = {0.f, 0.f, 0.f, 0.f};
    acc = mfma16(a1[0], cvt8(W2 + (nt * 16 + l15) * 64 + g * 8), acc);
    acc = mfma16(a1[1], cvt8(W2 + (nt * 16 + l15) * 64 + 32 + g * 8), acc);
    float bv = b2[nt * 16 + l15];
#pragma unroll
    for (int j = 0; j < 4; j++) {
      float h = acc[j] + bv;
      Tf[g * 4 + j][nt * 16 + l15]      = f2bf(__expf(h));
      Tf[g * 4 + j][64 + nt * 16 + l15] = f2bf(__expf(-h));
    }
  }
#pragma unroll
  for (int i = 0; i < 4; i++) {
    int c = i * 64 + l;
    int r = c >> 4, cc = c & 15;
    *(bf16x8*)(o2w + (r0 + r) * 128 + cc * 8) = *(const bf16x8*)&Tf[r][cc * 8];
  }
}

__global__ __launch_bounds__(256) void k_proj(
    const float* __restrict__ x,
    const float* __restrict__ Wq,  const float* __restrict__ bq,
    const float* __restrict__ Wk,  const float* __restrict__ bk,
    const float* __restrict__ Wmq, const float* __restrict__ bmq,
    const float* __restrict__ Wmk, const float* __restrict__ bmk,
    unsigned short* __restrict__ q0w, unsigned short* __restrict__ k0w,
    unsigned short* __restrict__ fqw, unsigned short* __restrict__ fkw)
{
  const int tid = threadIdx.x;
  const int w = tid >> 6, l = tid & 63;
  const int l15 = l & 15, g = l >> 4;
  const long r0 = ((long)blockIdx.x * 4 + w) * 16;

  __shared__ unsigned short TqS[4][16][72];
  __shared__ unsigned short TfS[4][16][136];

  bf16x8 ax[2];
#pragma unroll
  for (int kk = 0; kk < 2; kk++)
    ax[kk] = cvt8(x + (r0 + l15) * 64 + kk * 32 + g * 8);

  proj_chain(ax, Wq, bq, Wmq, bmq, q0w, fqw, TqS[w], TfS[w], r0, l15, g, l);
  proj_chain(ax, Wk, bk, Wmk, bmk, k0w, fkw, TqS[w], TfS[w], r0, l15, g, l);
}

// ---------------------------------------------------------------------------
// Kernel 2: fk column-sum partials (bh, part): rows part*256..+255.
// ---------------------------------------------------------------------------
__global__ __launch_bounds__(256) void k_colsum1(const unsigned short* __restrict__ fkw)
{
  const int bh = blockIdx.x, part = blockIdx.y;
  const int tid = threadIdx.x;
  const int cg = tid & 15, rg = tid >> 4;
  const unsigned short* fkp = fkw + ((long)bh * NN + part * 256 + rg * 16) * 128 + cg * 8;

  float a8[8] = {0.f, 0.f, 0.f, 0.f, 0.f, 0.f, 0.f, 0.f};
#pragma unroll
  for (int r = 0; r < 16; r++) {
    bf16x8 v = *(const bf16x8*)(fkp + (long)r * 128);
#pragma unroll
    for (int j = 0; j < 8; j++) a8[j] += bf2f((unsigned short)v[j]);
  }
  __shared__ float red[16][132];
#pragma unroll
  for (int j = 0; j < 8; j++) red[rg][cg * 8 + j] = a8[j];
  __syncthreads();
  if (tid < 128) {
    float s = 0.f;
#pragma unroll
    for (int r = 0; r < 16; r++) s += red[r][tid];
    g_part[(bh * 8 + part) * 128 + tid] = s;
  }
}

// ---------------------------------------------------------------------------
// Kernel 3: pipelined strip writer. Block = (bh, 16 q-rows), 8 waves.
// 16 chunks (8 pred + 8 true) of 16 rows x 256 cols. Per chunk:
//   prefetch next chunk's B-operands (regs) -> MFMA from prefetched regs ->
//   normalized fp32 to LDS buf[c&1] -> lgkmcnt(0) + raw s_barrier ->
//   2x 1KB nt stores per wave. No vmcnt(0) anywhere in the loop.
// ---------------------------------------------------------------------------
#define PREF(PN, C) {                                                          \
  const int cn_ = ((C) < 15) ? (C) + 1 : 15;                                   \
  const int pl_ = cn_ >> 3, kcn_ = (cn_ & 7) * 256;                            \
  if (pl_ == 0) {                                                              \
    _Pragma("unroll")                                                          \
    for (int i_ = 0; i_ < 2; i_++) {                                           \
      const unsigned short* bp_ = fkp + (long)(kcn_ + w32 + i_ * 16 + l15) * 128 + g * 8; \
      _Pragma("unroll")                                                        \
      for (int kk_ = 0; kk_ < 4; kk_++)                                        \
        PN[i_ * 4 + kk_] = *(const bf16x8*)(bp_ + kk_ * 32);                   \
    }                                                                          \
  } else {                                                                     \
    _Pragma("unroll")                                                          \
    for (int i_ = 0; i_ < 2; i_++) {                                           \
      const unsigned short* bp_ = k0p + (long)(kcn_ + w32 + i_ * 16 + l15) * 64 + g * 8;  \
      _Pragma("unroll")                                                        \
      for (int kk_ = 0; kk_ < 2; kk_++)                                        \
        PN[i_ * 2 + kk_] = *(const bf16x8*)(bp_ + kk_ * 32);                   \
    }                                                                          \
  }                                                                            \
}

#define BODY(C, PU, PN) {                                                      \
  PREF(PN, C);                                                                 \
  __builtin_amdgcn_sched_barrier(0);                                           \
  const int pl_ = (C) >> 3, kc_ = ((C) & 7) * 256;                             \
  float (*bufc_)[268] = buf[(C) & 1];                                          \
  if (pl_ == 0) {                                                              \
    _Pragma("unroll")                                                          \
    for (int i_ = 0; i_ < 2; i_++) {                                           \
      f32x4 acc_ = {0.f, 0.f, 0.f, 0.f};                                       \
      _Pragma("unroll")                                                        \
      for (int kk_ = 0; kk_ < 4; kk_++) acc_ = mfma16(afq[kk_], PU[i_*4+kk_], acc_); \
      _Pragma("unroll")                                                        \
      for (int j_ = 0; j_ < 4; j_++)                                           \
        bufc_[g * 4 + j_][w32 + i_ * 16 + l15] = acc_[j_] * ip[j_];            \
    }                                                                          \
  } else {                                                                     \
    _Pragma("unroll")                                                          \
    for (int i_ = 0; i_ < 2; i_++) {                                           \
      f32x4 acc_ = {0.f, 0.f, 0.f, 0.f};                                       \
      _Pragma("unroll")                                                        \
      for (int kk_ = 0; kk_ < 2; kk_++) acc_ = mfma16(aq0[kk_], PU[i_*2+kk_], acc_); \
      _Pragma("unroll")                                                        \
      for (int j_ = 0; j_ < 4; j_++)                                           \
        bufc_[g * 4 + j_][w32 + i_ * 16 + l15] = __expf(acc_[j_] * 0.125f) * it[j_]; \
    }                                                                          \
  }                                                                            \
  asm volatile("s_waitcnt lgkmcnt(0)" ::: "memory");                           \
  __builtin_amdgcn_s_barrier();                                                \
  __builtin_amdgcn_sched_barrier(0);                                           \
  {                                                                            \
    const long ob_ = (pl_ ? ob_t : ob_p) + kc_;                                \
    _Pragma("unroll")                                                          \
    for (int r_ = 0; r_ < 2; r_++) {                                           \
      const int row_ = w * 2 + r_;                                             \
      f32x4 v_ = *(const f32x4*)&bufc_[row_][l * 4];                           \
      __builtin_nontemporal_store(v_, (f32x4*)(out + ob_ + (long)row_ * NN + l * 4)); \
    }                                                                          \
  }                                                                            \
}

__global__ __launch_bounds__(512, 4) void k_write(
    const unsigned short* __restrict__ q0w, const unsigned short* __restrict__ k0w,
    const unsigned short* __restrict__ fqw, const unsigned short* __restrict__ fkw,
    float* __restrict__ out)
{
  const int bh = blockIdx.x;          // 0..31
  const int rq = blockIdx.y;          // 0..127
  const int tid = threadIdx.x;
  const int w = tid >> 6, l = tid & 63;
  const int l15 = l & 15, g = l >> 4;
  const int w32 = w * 32;
  const int qrow0 = rq * 16;

  __shared__ float buf[2][16][268];   // double-buffered 16x256 chunk
  __shared__ float sred[8][16];

  // ---- A fragments (all waves: same 16 rows) ----
  const unsigned short* fqp = fqw + ((long)bh * NN + qrow0) * 128;
  bf16x8 afq[4];
#pragma unroll
  for (int kk = 0; kk < 4; kk++)
    afq[kk] = *(const bf16x8*)(fqp + l15 * 128 + kk * 32 + g * 8);
  const unsigned short* q0p = q0w + ((long)bh * NN + qrow0) * 64;
  bf16x8 aq0[2];
#pragma unroll
  for (int kk = 0; kk < 2; kk++)
    aq0[kk] = *(const bf16x8*)(q0p + l15 * 64 + kk * 32 + g * 8);

  const unsigned short* fkp = fkw + (long)bh * NN * 128;
  const unsigned short* k0p = k0w + (long)bh * NN * 64;

  // ---- pred reciprocals: ip = 1 / (fq[row] . Sfk) ----
  float dotv = 0.f;
  {
    const unsigned short* p = fqp + (long)l15 * 128 + g * 32;
    const float* pp = g_part + bh * 1024 + g * 32;
#pragma unroll
    for (int i = 0; i < 32; i += 8) {
      bf16x8 v = *(const bf16x8*)(p + i);
#pragma unroll
      for (int jj = 0; jj < 8; jj++) {
        float s = 0.f;
#pragma unroll
        for (int pt = 0; pt < 8; pt++) s += pp[pt * 128 + i + jj];
        dotv += bf2f((unsigned short)v[jj]) * s;
      }
    }
  }
  dotv += __shfl_xor(dotv, 16, 64);
  dotv += __shfl_xor(dotv, 32, 64);
  float ip[4];
#pragma unroll
  for (int j = 0; j < 4; j++)
    ip[j] = 1.0f / __shfl(dotv, (g * 4 + j) & 15, 16);

  // ---- true row sums (keys split across 8 waves, LDS combine) ----
  float st[4] = {0.f, 0.f, 0.f, 0.f};
  for (int t = w; t < 128; t += 8) {
    const unsigned short* bp = k0p + (long)(t * 16 + l15) * 64 + g * 8;
    f32x4 acc = {0.f, 0.f, 0.f, 0.f};
    acc = mfma16(aq0[0], *(const bf16x8*)bp, acc);
    acc = mfma16(aq0[1], *(const bf16x8*)(bp + 32), acc);
#pragma unroll
    for (int j = 0; j < 4; j++) st[j] += __expf(acc[j] * 0.125f);
  }
#pragma unroll
  for (int j = 0; j < 4; j++) {
    float v = st[j];
    v += __shfl_xor(v, 1, 16);
    v += __shfl_xor(v, 2, 16);
    v += __shfl_xor(v, 4, 16);
    v += __shfl_xor(v, 8, 16);
    if (l15 == 0) sred[w][g * 4 + j] = v;
  }
  __syncthreads();
  float it[4];
#pragma unroll
  for (int j = 0; j < 4; j++) {
    float s = 0.f;
#pragma unroll
    for (int ww = 0; ww < 8; ww++) s += sred[ww][g * 4 + j];
    it[j] = 1.0f / s;
  }

  // ---- pipelined chunk loop: 8 pred chunks then 8 true chunks ----
  const long ob_p = (long)bh * NN * NN + (long)qrow0 * NN;
  const long ob_t = ob_p + (long)NBH * NN * NN;

  bf16x8 pa[8], pb[8];
  PREF(pa, -1);                       // chunk 0 operands
  for (int cc = 0; cc < 16; cc += 2) {
    BODY(cc,     pa, pb);
    BODY(cc + 1, pb, pa);
  }
}

extern "C" void kernel_launch(void* const* d_in, const int* in_sizes, int n_in,
                              void* d_out, int out_size, void* d_ws, size_t ws_size,
                              hipStream_t stream) {
  const float* x   = (const float*)d_in[0];
  const float* Wq  = (const float*)d_in[1];
  const float* bq  = (const float*)d_in[2];
  const float* Wk  = (const float*)d_in[3];
  const float* bk  = (const float*)d_in[4];
  const float* Wmq = (const float*)d_in[5];
  const float* bmq = (const float*)d_in[6];
  const float* Wmk = (const float*)d_in[7];
  const float* bmk = (const float*)d_in[8];
  float* out = (float*)d_out;

  // ws layout (bf16): q0[32][2048][64], k0[...], fq[32][2048][128], fk[...] = 48 MB
  unsigned short* q0w = (unsigned short*)d_ws;
  unsigned short* k0w = q0w + (long)NBH * NN * 64;
  unsigned short* fqw = k0w + (long)NBH * NN * 64;
  unsigned short* fkw = fqw + (long)NBH * NN * 128;

  hipLaunchKernelGGL(k_proj, dim3(1024), dim3(256), 0, stream,
                     x, Wq, bq, Wk, bk, Wmq, bmq, Wmk, bmk, q0w, k0w, fqw, fkw);
  hipLaunchKernelGGL(k_colsum1, dim3(NBH, 8), dim3(256), 0, stream, fkw);
  hipLaunchKernelGGL(k_write, dim3(NBH, 128), dim3(512), 0, stream,
                     q0w, k0w, fqw, fkw, out);
}

// Round 7
// 597.403 us; speedup vs baseline: 1.1084x; 1.1084x over previous
//
#include <hip/hip_runtime.h>

// ---------------------------------------------------------------------------
// HedgeHog attention distillation map: pred = (fq.fk^T) rownorm, true = softmax(q0.k0^T/8)
// Output [2,2,16,2048,2048] fp32 = 1.07 GiB -> HBM-write-bound (~165us floor).
//
// v7: de-resonate the write streams. All prior variants had 64 concurrent
// write streams at EXACT 32MB/512MB (pow2) offsets advancing in lockstep ->
// all streams on the same DRAM channel phase -> ~2 TB/s. Fill (6.5 TB/s) has
// non-resonant stream offsets. Fix: scramble row-group assignment per bh
// (rq_eff = rq + 37*bh mod 128), rotate 1KB segments and half-order per
// block, plain (non-nt) stores. Structure otherwise = v5 (64KB LDS staging,
// address-ordered 4KB row runs).
// ---------------------------------------------------------------------------

typedef __attribute__((ext_vector_type(8))) short  bf16x8;
typedef __attribute__((ext_vector_type(4))) float  f32x4;

#define NN 2048
#define NBH 32

__device__ float g_part[NBH * 8 * 128];   // fk colsum partials

__device__ __forceinline__ float bf2f(unsigned short u) {
  union { unsigned int i; float f; } v; v.i = ((unsigned int)u) << 16; return v.f;
}
__device__ __forceinline__ unsigned short f2bf(float f) {
  union { float f; unsigned int i; } v; v.f = f;
  unsigned int x = v.i;
  return (unsigned short)((x + 0x7FFFu + ((x >> 16) & 1u)) >> 16);  // RNE
}
__device__ __forceinline__ bf16x8 cvt8(const float* __restrict__ p) {
  bf16x8 v;
#pragma unroll
  for (int i = 0; i < 8; i++) v[i] = (short)f2bf(p[i]);
  return v;
}
__device__ __forceinline__ f32x4 mfma16(bf16x8 a, bf16x8 b, f32x4 c) {
  return __builtin_amdgcn_mfma_f32_16x16x32_bf16(a, b, c, 0, 0, 0);
}

// ---------------------------------------------------------------------------
// Kernel 1: projections + hedgehog features. One wave owns 16 rows.
// ---------------------------------------------------------------------------
__device__ __forceinline__ void proj_chain(
    const bf16x8 ax[2],
    const float* __restrict__ W1, const float* __restrict__ b1,
    const float* __restrict__ W2, const float* __restrict__ b2,
    unsigned short* __restrict__ o1w, unsigned short* __restrict__ o2w,
    unsigned short (*Tq)[72], unsigned short (*Tf)[136],
    long r0, int l15, int g, int l)
{
#pragma unroll
  for (int nt = 0; nt < 4; nt++) {
    f32x4 acc = {0.f, 0.f, 0.f, 0.f};
    acc = mfma16(ax[0], cvt8(W1 + (nt * 16 + l15) * 64 + g * 8), acc);
    acc = mfma16(ax[1], cvt8(W1 + (nt * 16 + l15) * 64 + 32 + g * 8), acc);
    float bv = b1[nt * 16 + l15];
#pragma unroll
    for (int j = 0; j < 4; j++)
      Tq[g * 4 + j][nt * 16 + l15] = f2bf(acc[j] + bv);   // C layout: row=(l>>4)*4+j, col=l&15
  }
#pragma unroll
  for (int i = 0; i < 2; i++) {
    int c = i * 64 + l;
    int r = c >> 3, cc = c & 7;
    *(bf16x8*)(o1w + (r0 + r) * 64 + cc * 8) = *(const bf16x8*)&Tq[r][cc * 8];
  }
  bf16x8 a1[2];
#pragma unroll
  for (int kk = 0; kk < 2; kk++)
    a1[kk] = *(const bf16x8*)&Tq[l15][kk * 32 + g * 8];
#pragma unroll
  for (int nt = 0; nt < 4; nt++) {
    f32x4 acc = {0.f, 0.f, 0.f, 0.f};
    acc = mfma16(a1[0], cvt8(W2 + (nt * 16 + l15) * 64 + g * 8), acc);
    acc = mfma16(a1[1], cvt8(W2 + (nt * 16 + l15) * 64 + 32 + g * 8), acc);
    float bv = b2[nt * 16 + l15];
#pragma unroll
    for (int j = 0; j < 4; j++) {
      float h = acc[j] + bv;
      Tf[g * 4 + j][nt * 16 + l15]      = f2bf(__expf(h));
      Tf[g * 4 + j][64 + nt * 16 + l15] = f2bf(__expf(-h));
    }
  }
#pragma unroll
  for (int i = 0; i < 4; i++) {
    int c = i * 64 + l;
    int r = c >> 4, cc = c & 15;
    *(bf16x8*)(o2w + (r0 + r) * 128 + cc * 8) = *(const bf16x8*)&Tf[r][cc * 8];
  }
}

__global__ __launch_bounds__(256) void k_proj(
    const float* __restrict__ x,
    const float* __restrict__ Wq,  const float* __restrict__ bq,
    const float* __restrict__ Wk,  const float* __restrict__ bk,
    const float* __restrict__ Wmq, const float* __restrict__ bmq,
    const float* __restrict__ Wmk, const float* __restrict__ bmk,
    unsigned short* __restrict__ q0w, unsigned short* __restrict__ k0w,
    unsigned short* __restrict__ fqw, unsigned short* __restrict__ fkw)
{
  const int tid = threadIdx.x;
  const int w = tid >> 6, l = tid & 63;
  const int l15 = l & 15, g = l >> 4;
  const long r0 = ((long)blockIdx.x * 4 + w) * 16;

  __shared__ unsigned short TqS[4][16][72];
  __shared__ unsigned short TfS[4][16][136];

  bf16x8 ax[2];
#pragma unroll
  for (int kk = 0; kk < 2; kk++)
    ax[kk] = cvt8(x + (r0 + l15) * 64 + kk * 32 + g * 8);

  proj_chain(ax, Wq, bq, Wmq, bmq, q0w, fqw, TqS[w], TfS[w], r0, l15, g, l);
  proj_chain(ax, Wk, bk, Wmk, bmk, k0w, fkw, TqS[w], TfS[w], r0, l15, g, l);
}

// ---------------------------------------------------------------------------
// Kernel 2: fk column-sum partials (bh, part): rows part*256..+255.
// ---------------------------------------------------------------------------
__global__ __launch_bounds__(256) void k_colsum1(const unsigned short* __restrict__ fkw)
{
  const int bh = blockIdx.x, part = blockIdx.y;
  const int tid = threadIdx.x;
  const int cg = tid & 15, rg = tid >> 4;
  const unsigned short* fkp = fkw + ((long)bh * NN + part * 256 + rg * 16) * 128 + cg * 8;

  float a8[8] = {0.f, 0.f, 0.f, 0.f, 0.f, 0.f, 0.f, 0.f};
#pragma unroll
  for (int r = 0; r < 16; r++) {
    bf16x8 v = *(const bf16x8*)(fkp + (long)r * 128);
#pragma unroll
    for (int j = 0; j < 8; j++) a8[j] += bf2f((unsigned short)v[j]);
  }
  __shared__ float red[16][132];
#pragma unroll
  for (int j = 0; j < 8; j++) red[rg][cg * 8 + j] = a8[j];
  __syncthreads();
  if (tid < 128) {
    float s = 0.f;
#pragma unroll
    for (int r = 0; r < 16; r++) s += red[r][tid];
    g_part[(bh * 8 + part) * 128 + tid] = s;
  }
}

// ---------------------------------------------------------------------------
// Kernel 3: strip writer (v5 structure + de-resonance). Block = (bh, rq) but
// processes row-group rq_eff = (rq + 37*bh) & 127 so concurrent blocks write
// at non-pow2-correlated addresses. 4 phases: {pred,true} x {half0,half1},
// plane and half order rotated per block; 1KB segments rotated per block.
// ---------------------------------------------------------------------------
__global__ __launch_bounds__(256, 2) void k_write(
    const unsigned short* __restrict__ q0w, const unsigned short* __restrict__ k0w,
    const unsigned short* __restrict__ fqw, const unsigned short* __restrict__ fkw,
    float* __restrict__ out)
{
  const int bh = blockIdx.x;          // 0..31
  const int rq = blockIdx.y;          // 0..127
  const int tid = threadIdx.x;
  const int w = tid >> 6, l = tid & 63;
  const int l15 = l & 15, g = l >> 4;
  const int rqe = (rq + bh * 37) & 127;   // de-resonance row-group scramble
  const int qrow0 = rqe * 16;

  __shared__ float buf[16][1028];     // 64KB half-strip (stride 1028: 2-way-free)
  __shared__ float sred[4][16];

  // ---- A fragments ----
  const unsigned short* fqp = fqw + ((long)bh * NN + qrow0) * 128;
  bf16x8 afq[4];
#pragma unroll
  for (int kk = 0; kk < 4; kk++)
    afq[kk] = *(const bf16x8*)(fqp + l15 * 128 + kk * 32 + g * 8);
  const unsigned short* q0p = q0w + ((long)bh * NN + qrow0) * 64;
  bf16x8 aq0[2];
#pragma unroll
  for (int kk = 0; kk < 2; kk++)
    aq0[kk] = *(const bf16x8*)(q0p + l15 * 64 + kk * 32 + g * 8);

  const unsigned short* fkp = fkw + (long)bh * NN * 128;
  const unsigned short* k0p = k0w + (long)bh * NN * 64;

  // ---- pred reciprocals: ip = 1 / (fq[row] . Sfk) ----
  float dotv = 0.f;
  {
    const unsigned short* p = fqp + (long)l15 * 128 + g * 32;
    const float* pp = g_part + bh * 1024 + g * 32;
#pragma unroll
    for (int i = 0; i < 32; i += 8) {
      bf16x8 v = *(const bf16x8*)(p + i);
#pragma unroll
      for (int jj = 0; jj < 8; jj++) {
        float s = 0.f;
#pragma unroll
        for (int pt = 0; pt < 8; pt++) s += pp[pt * 128 + i + jj];
        dotv += bf2f((unsigned short)v[jj]) * s;
      }
    }
  }
  dotv += __shfl_xor(dotv, 16, 64);
  dotv += __shfl_xor(dotv, 32, 64);
  float ip[4];
#pragma unroll
  for (int j = 0; j < 4; j++)
    ip[j] = 1.0f / __shfl(dotv, (g * 4 + j) & 15, 16);

  // ---- true row sums (keys split across waves, LDS combine) ----
  float st[4] = {0.f, 0.f, 0.f, 0.f};
  for (int t = w; t < 128; t += 4) {
    const unsigned short* bp = k0p + (long)(t * 16 + l15) * 64 + g * 8;
    f32x4 acc = {0.f, 0.f, 0.f, 0.f};
    acc = mfma16(aq0[0], *(const bf16x8*)bp, acc);
    acc = mfma16(aq0[1], *(const bf16x8*)(bp + 32), acc);
#pragma unroll
    for (int j = 0; j < 4; j++) st[j] += __expf(acc[j] * 0.125f);
  }
#pragma unroll
  for (int j = 0; j < 4; j++) {
    float v = st[j];
    v += __shfl_xor(v, 1, 16);
    v += __shfl_xor(v, 2, 16);
    v += __shfl_xor(v, 4, 16);
    v += __shfl_xor(v, 8, 16);
    if (l15 == 0) sred[w][g * 4 + j] = v;
  }
  __syncthreads();
  float it[4];
#pragma unroll
  for (int j = 0; j < 4; j++)
    it[j] = 1.0f / (sred[0][g * 4 + j] + sred[1][g * 4 + j] +
                    sred[2][g * 4 + j] + sred[3][g * 4 + j]);
  __syncthreads();

  // ---- 4 phases: plane x half, plane+half order rotated per block ----
  const long ob_p = (long)bh * NN * NN + (long)qrow0 * NN;
  const long ob_t = ob_p + (long)NBH * NN * NN;
  const int sw = (bh ^ rq) & 1;
  const int hw = (bh >> 1) & 1;
  const int srot = (bh ^ rq) & 3;

  for (int ph = 0; ph < 4; ph++) {
    const int plane = (ph >> 1) ^ sw;   // 0=pred, 1=true
    const int h = (ph & 1) ^ hw;        // column half
    if (plane == 0) {
#pragma unroll
      for (int tt = 0; tt < 16; tt++) {
        const int colh = w * 256 + tt * 16;
        const unsigned short* bp = fkp + (long)(h * 1024 + colh + l15) * 128 + g * 8;
        f32x4 acc = {0.f, 0.f, 0.f, 0.f};
#pragma unroll
        for (int kk = 0; kk < 4; kk++)
          acc = mfma16(afq[kk], *(const bf16x8*)(bp + kk * 32), acc);
#pragma unroll
        for (int j = 0; j < 4; j++)
          buf[g * 4 + j][colh + l15] = acc[j] * ip[j];
      }
    } else {
#pragma unroll
      for (int tt = 0; tt < 16; tt++) {
        const int colh = w * 256 + tt * 16;
        const unsigned short* bp = k0p + (long)(h * 1024 + colh + l15) * 64 + g * 8;
        f32x4 acc = {0.f, 0.f, 0.f, 0.f};
        acc = mfma16(aq0[0], *(const bf16x8*)bp, acc);
        acc = mfma16(aq0[1], *(const bf16x8*)(bp + 32), acc);
#pragma unroll
        for (int j = 0; j < 4; j++)
          buf[g * 4 + j][colh + l15] = __expf(acc[j] * 0.125f) * it[j];
      }
    }
    __syncthreads();
    // store: wave w -> rows 4w..4w+3, 4KB runs, segments rotated per block
    {
      const long ob = (plane == 0 ? ob_p : ob_t) + h * 1024;
#pragma unroll
      for (int r = 0; r < 4; r++) {
        const int row = w * 4 + r;
        float* orow = out + ob + (long)row * NN;
#pragma unroll
        for (int i = 0; i < 4; i++) {
          const int seg = (i + srot) & 3;
          f32x4 v = *(const f32x4*)&buf[row][seg * 256 + l * 4];
          *(f32x4*)(orow + seg * 256 + l * 4) = v;
        }
      }
    }
    __syncthreads();
  }
}

extern "C" void kernel_launch(void* const* d_in, const int* in_sizes, int n_in,
                              void* d_out, int out_size, void* d_ws, size_t ws_size,
                              hipStream_t stream) {
  const float* x   = (const float*)d_in[0];
  const float* Wq  = (const float*)d_in[1];
  const float* bq  = (const float*)d_in[2];
  const float* Wk  = (const float*)d_in[3];
  const float* bk  = (const float*)d_in[4];
  const float* Wmq = (const float*)d_in[5];
  const float* bmq = (const float*)d_in[6];
  const float* Wmk = (const float*)d_in[7];
  const float* bmk = (const float*)d_in[8];
  float* out = (float*)d_out;

  // ws layout (bf16): q0[32][2048][64], k0[...], fq[32][2048][128], fk[...] = 48 MB
  unsigned short* q0w = (unsigned short*)d_ws;
  unsigned short* k0w = q0w + (long)NBH * NN * 64;
  unsigned short* fqw = k0w + (long)NBH * NN * 64;
  unsigned short* fkw = fqw + (long)NBH * NN * 128;

  hipLaunchKernelGGL(k_proj, dim3(1024), dim3(256), 0, stream,
                     x, Wq, bq, Wk, bk, Wmq, bmq, Wmk, bmk, q0w, k0w, fqw, fkw);
  hipLaunchKernelGGL(k_colsum1, dim3(NBH, 8), dim3(256), 0, stream, fkw);
  hipLaunchKernelGGL(k_write, dim3(NBH, 128), dim3(256), 0, stream,
                     q0w, k0w, fqw, fkw, out);
}